// Round 1
// baseline (615.284 us; speedup 1.0000x reference)
//
#include <hip/hip_runtime.h>
#include <cstdint>
#include <cstddef>

#define EE 1000000
#define NN 100000

typedef unsigned short u16;
typedef __bf16 bf16x8 __attribute__((ext_vector_type(8)));
typedef float f32x4 __attribute__((ext_vector_type(4)));

__device__ __forceinline__ u16 f2bf(float f) {
    union { float f; uint32_t u; } v; v.f = f;
    uint32_t r = v.u + 0x7FFFu + ((v.u >> 16) & 1u);   // RNE
    return (u16)(r >> 16);
}
__device__ __forceinline__ uint32_t f2bf2(float lo, float hi) {
    return (uint32_t)f2bf(lo) | ((uint32_t)f2bf(hi) << 16);
}

// ---------------- prep: pack W1[384][128], W2[128][128] fp32 -> bf16 fragment stream
// layout: idx = ((ks*8 + ct)*64 + lane)*8 + j  ->  W[ks*32 + (lane>>4)*8 + j][ct*16 + (lane&15)]
__global__ void pack_weights_k(const float* __restrict__ W1, const float* __restrict__ W2,
                               u16* __restrict__ pack) {
    int t = blockIdx.x * 256 + threadIdx.x;
    if (t < 49152) {
        int j = t & 7, lane = (t >> 3) & 63, ct = (t >> 9) & 7, ks = t >> 12;
        int k = ks * 32 + ((lane >> 4) << 3) + j;
        int col = (ct << 4) + (lane & 15);
        pack[t] = f2bf(W1[k * 128 + col]);
    } else if (t < 65536) {
        int u = t - 49152;
        int j = u & 7, lane = (u >> 3) & 63, ct = (u >> 9) & 7, ks = u >> 12;
        int k = ks * 32 + ((lane >> 4) << 3) + j;
        int col = (ct << 4) + (lane & 15);
        pack[t] = f2bf(W2[k * 128 + col]);
    }
}

// ---------------- output[1] = nfeat passthrough
__global__ void copy_nfeat_k(const float4* __restrict__ s, float4* __restrict__ d, int n) {
    for (int i = blockIdx.x * blockDim.x + threadIdx.x; i < n; i += gridDim.x * blockDim.x)
        d[i] = s[i];
}

// ---------------- main fused kernel
// block: 512 threads = 8 waves (4 row-groups x 2 col-groups), tile = 128 edges
// LDS: [0,96K) W1 frags, [96K,128K) cat chunk double-buffer / h frags / LN scratch
__launch_bounds__(512, 2)
__global__ void edge_mlp_k(const float* __restrict__ efeat, const float* __restrict__ nfeat,
                           const int* __restrict__ srci, const int* __restrict__ dsti,
                           const u16* __restrict__ pack,
                           const float* __restrict__ b1p, const float* __restrict__ b2p,
                           const float* __restrict__ gp, const float* __restrict__ bp,
                           float* __restrict__ out) {
    extern __shared__ char smem[];
    u16* w1 = (u16*)smem;                    // 49152 u16
    u16* cbuf = (u16*)(smem + 98304);        // 16384 u16 (2x8192 stage bufs; later h; later LN)
    float* lnbuf = (float*)(smem + 98304);

    const int tid = threadIdx.x;
    const int lane = tid & 63;
    const int wid = tid >> 6;
    const int wr = wid >> 1;   // 0..3: rows wr*32..wr*32+31
    const int wc = wid & 1;    // 0..1: cols wc*64..wc*64+63

    // W1 -> LDS (linear image, coalesced)
    {
        const uint4* g = (const uint4*)pack;   // W1 = 6144 uint4
        uint4* l = (uint4*)smem;
#pragma unroll
        for (int i = 0; i < 12; i++) l[tid + i * 512] = g[tid + i * 512];
    }
    // W2 fragments -> registers (16 x bf16x8 = 64 VGPR)
    bf16x8 w2f[4][4];
    {
        const bf16x8* g = (const bf16x8*)(pack + 49152);
#pragma unroll
        for (int ks = 0; ks < 4; ks++)
#pragma unroll
            for (int ct = 0; ct < 4; ct++)
                w2f[ks][ct] = g[(ks * 8 + wc * 4 + ct) * 64 + lane];
    }
    float b1v[4], b2v[4], gv[4], bv[4];
#pragma unroll
    for (int ct = 0; ct < 4; ct++) {
        int col = wc * 64 + ct * 16 + (lane & 15);
        b1v[ct] = b1p[col]; b2v[ct] = b2p[col]; gv[ct] = gp[col]; bv[ct] = bp[col];
    }
    __syncthreads();

    const int srow = tid & 127;   // staging row within tile
    const int skc = tid >> 7;     // 0..3: 16-float column slice of 64-wide chunk

    const int numTiles = (EE + 127) >> 7;
    for (int tile = blockIdx.x; tile < numTiles; tile += gridDim.x) {
        const int base = tile << 7;
        int e_s = base + srow; if (e_s >= EE) e_s = EE - 1;
        const int sn = srci[e_s];
        const int dn = dsti[e_s];
        const float* rowp[3];
        rowp[0] = efeat + (size_t)e_s * 128;
        rowp[1] = nfeat + (size_t)sn * 128;
        rowp[2] = nfeat + (size_t)dn * 128;

        f32x4 acc1[2][4] = {};
        float4 L0, L1, L2, L3;

        // chunk c covers cat K-range [c*64, c*64+64): c 0-1 efeat, 2-3 src, 4-5 dst.
        // Process order {2,3,4,5,0,1} so efeat (needed again in epilogue) is read last.
#define SLOAD(c) { const float4* p4_ = (const float4*)(rowp[(c) >> 1] + (((c) & 1) * 64 + skc * 16)); \
        L0 = p4_[0]; L1 = p4_[1]; L2 = p4_[2]; L3 = p4_[3]; }

#define SWRITE(ci) { u16* buf_ = cbuf + ((ci) & 1) * 8192; \
        int rt_ = srow >> 4; \
        uint4 q0_, q1_; \
        q0_.x = f2bf2(L0.x, L0.y); q0_.y = f2bf2(L0.z, L0.w); \
        q0_.z = f2bf2(L1.x, L1.y); q0_.w = f2bf2(L1.z, L1.w); \
        q1_.x = f2bf2(L2.x, L2.y); q1_.y = f2bf2(L2.z, L2.w); \
        q1_.z = f2bf2(L3.x, L3.y); q1_.w = f2bf2(L3.z, L3.w); \
        int kk0_ = skc * 2; \
        int ksl0_ = kk0_ >> 2;      int la0_ = (srow & 15) + ((kk0_ & 3) << 4); \
        int ksl1_ = (kk0_ + 1) >> 2; int la1_ = (srow & 15) + (((kk0_ + 1) & 3) << 4); \
        *(uint4*)(buf_ + ((rt_ * 2 + ksl0_) * 64 + la0_) * 8) = q0_; \
        *(uint4*)(buf_ + ((rt_ * 2 + ksl1_) * 64 + la1_) * 8) = q1_; }

#define GCHUNK(c, ci) { const u16* buf_ = cbuf + ((ci) & 1) * 8192; \
        _Pragma("unroll") \
        for (int ksl = 0; ksl < 2; ksl++) { \
            int ks_ = (c) * 2 + ksl; \
            bf16x8 a0_ = *(const bf16x8*)(buf_ + (((wr * 2 + 0) * 2 + ksl) * 64 + lane) * 8); \
            bf16x8 a1_ = *(const bf16x8*)(buf_ + (((wr * 2 + 1) * 2 + ksl) * 64 + lane) * 8); \
            _Pragma("unroll") \
            for (int ct = 0; ct < 4; ct++) { \
                bf16x8 b_ = *(const bf16x8*)(w1 + ((ks_ * 8 + wc * 4 + ct) * 64 + lane) * 8); \
                acc1[0][ct] = __builtin_amdgcn_mfma_f32_16x16x32_bf16(a0_, b_, acc1[0][ct], 0, 0, 0); \
                acc1[1][ct] = __builtin_amdgcn_mfma_f32_16x16x32_bf16(a1_, b_, acc1[1][ct], 0, 0, 0); \
            } } }

        SLOAD(2); SWRITE(0);
        __syncthreads();
        SLOAD(3); GCHUNK(2, 0); SWRITE(1); __syncthreads();
        SLOAD(4); GCHUNK(3, 1); SWRITE(2); __syncthreads();
        SLOAD(5); GCHUNK(4, 2); SWRITE(3); __syncthreads();
        SLOAD(0); GCHUNK(5, 3); SWRITE(4); __syncthreads();
        SLOAD(1); GCHUNK(0, 4); SWRITE(5); __syncthreads();
        GCHUNK(1, 5); __syncthreads();

        // bias + SiLU, write h into GEMM2 A-fragment layout (reuses cbuf 32KB)
#pragma unroll
        for (int rtl = 0; rtl < 2; rtl++) {
            int rt = wr * 2 + rtl;
#pragma unroll
            for (int ct = 0; ct < 4; ct++) {
                int ks = wc * 2 + (ct >> 1);
                int lahi = ((ct & 1) * 2) + ((lane & 15) >> 3);
                int j = lane & 7;
#pragma unroll
                for (int r = 0; r < 4; r++) {
                    float x = acc1[rtl][ct][r] + b1v[ct];
                    float s = x / (1.f + __expf(-x));
                    int la = ((lane >> 4) * 4 + r) + (lahi << 4);
                    cbuf[((rt * 4 + ks) * 64 + la) * 8 + j] = f2bf(s);
                }
            }
        }
        __syncthreads();

        // GEMM2: h[128][128] @ W2 -> acc2
        f32x4 acc2[2][4] = {};
#pragma unroll
        for (int ks2 = 0; ks2 < 4; ks2++) {
            bf16x8 a0 = *(const bf16x8*)(cbuf + (((wr * 2 + 0) * 4 + ks2) * 64 + lane) * 8);
            bf16x8 a1 = *(const bf16x8*)(cbuf + (((wr * 2 + 1) * 4 + ks2) * 64 + lane) * 8);
#pragma unroll
            for (int ct = 0; ct < 4; ct++) {
                acc2[0][ct] = __builtin_amdgcn_mfma_f32_16x16x32_bf16(a0, w2f[ks2][ct], acc2[0][ct], 0, 0, 0);
                acc2[1][ct] = __builtin_amdgcn_mfma_f32_16x16x32_bf16(a1, w2f[ks2][ct], acc2[1][ct], 0, 0, 0);
            }
        }
        __syncthreads();   // h reads done; cbuf reusable as LN scratch

        // LayerNorm partials: per-row sum/sumsq over this wave's 64 cols
#pragma unroll
        for (int rtl = 0; rtl < 2; rtl++) {
#pragma unroll
            for (int r = 0; r < 4; r++) {
                float s = 0.f, q = 0.f;
#pragma unroll
                for (int ct = 0; ct < 4; ct++) {
                    float x = acc2[rtl][ct][r] + b2v[ct];
                    s += x; q += x * x;
                }
#pragma unroll
                for (int m = 1; m < 16; m <<= 1) { s += __shfl_xor(s, m); q += __shfl_xor(q, m); }
                if ((lane & 15) == 0) {
                    int row = wr * 32 + rtl * 16 + (lane >> 4) * 4 + r;
                    lnbuf[row * 4 + wc * 2 + 0] = s;
                    lnbuf[row * 4 + wc * 2 + 1] = q;
                }
            }
        }
        __syncthreads();

        // finalize LN, + efeat residual, store
#pragma unroll
        for (int rtl = 0; rtl < 2; rtl++) {
#pragma unroll
            for (int r = 0; r < 4; r++) {
                int row = wr * 32 + rtl * 16 + (lane >> 4) * 4 + r;
                int e = base + row;
                float mean = (lnbuf[row * 4 + 0] + lnbuf[row * 4 + 2]) * (1.f / 128.f);
                float msq  = (lnbuf[row * 4 + 1] + lnbuf[row * 4 + 3]) * (1.f / 128.f);
                float rstd = rsqrtf(msq - mean * mean + 1e-5f);
                if (e < EE) {
                    const float* ef = efeat + (size_t)e * 128;
                    float* op = out + (size_t)e * 128;
#pragma unroll
                    for (int ct = 0; ct < 4; ct++) {
                        int col = wc * 64 + ct * 16 + (lane & 15);
                        float x = acc2[rtl][ct][r] + b2v[ct];
                        op[col] = (x - mean) * rstd * gv[ct] + bv[ct] + ef[col];
                    }
                }
            }
        }
        __syncthreads();   // protect lnbuf/cbuf before next tile's staging
#undef SLOAD
#undef SWRITE
#undef GCHUNK
    }
}

extern "C" void kernel_launch(void* const* d_in, const int* in_sizes, int n_in,
                              void* d_out, int out_size, void* d_ws, size_t ws_size,
                              hipStream_t stream) {
    const float* efeat = (const float*)d_in[0];
    const float* nfeat = (const float*)d_in[1];
    const int* srci = (const int*)d_in[2];
    const int* dsti = (const int*)d_in[3];
    const float* W1 = (const float*)d_in[4];
    const float* b1 = (const float*)d_in[5];
    const float* W2 = (const float*)d_in[6];
    const float* b2 = (const float*)d_in[7];
    const float* lng = (const float*)d_in[8];
    const float* lnb = (const float*)d_in[9];
    float* out = (float*)d_out;

    // 128 KB of packed bf16 weights; fall back to the (later overwritten) nfeat
    // output region if the workspace is too small.
    u16* pack = (ws_size >= 131072) ? (u16*)d_ws : (u16*)(out + (size_t)EE * 128);

    hipFuncSetAttribute(reinterpret_cast<const void*>(edge_mlp_k),
                        hipFuncAttributeMaxDynamicSharedMemorySize, 131072);

    pack_weights_k<<<256, 256, 0, stream>>>(W1, W2, pack);
    edge_mlp_k<<<256, 512, 131072, stream>>>(efeat, nfeat, srci, dsti, pack,
                                             b1, b2, lng, lnb, out);
    copy_nfeat_k<<<2048, 256, 0, stream>>>((const float4*)nfeat,
                                           (float4*)(out + (size_t)EE * 128),
                                           (NN * 128) / 4);
}